// Round 3
// baseline (121.081 us; speedup 1.0000x reference)
//
#include <hip/hip_runtime.h>
#include <hip/hip_bf16.h>
#include <stdint.h>

#define NROW 4096
#define DIM  512
#define NT64 (NROW / 64)            // 64 tiles per dim
#define NTRI (NT64 * (NT64 + 1) / 2)  // 2080 triangular 64x64 tiles
#define NKS  (DIM / 32)             // 16 k-steps of 32

typedef __attribute__((ext_vector_type(8))) short  short8;   // 8 bf16 = 4 VGPRs
typedef __attribute__((ext_vector_type(4))) float  floatx4;  // MFMA 16x16 C/D

__device__ __forceinline__ unsigned short f32_to_bf16_rne(float f) {
    unsigned u = __float_as_uint(f);
    u += 0x7FFFu + ((u >> 16) & 1u);
    return (unsigned short)(u >> 16);
}

// 256 threads: wave w handles row blockIdx*4+w. fp32 row norm, bf16 convert,
// out zeroing (harness poisons d_out/d_ws with 0xAA before every launch).
__global__ __launch_bounds__(256) void prep_kernel(
    const float* __restrict__ X, unsigned short* __restrict__ Xb,
    float* __restrict__ sq, float* __restrict__ out)
{
    const int wave = threadIdx.x >> 6;
    const int lane = threadIdx.x & 63;
    const int row  = blockIdx.x * 4 + wave;
    const float4* xr = (const float4*)(X + (size_t)row * DIM);
    float4 v0 = xr[2 * lane];
    float4 v1 = xr[2 * lane + 1];
    float s = v0.x*v0.x + v0.y*v0.y + v0.z*v0.z + v0.w*v0.w
            + v1.x*v1.x + v1.y*v1.y + v1.z*v1.z + v1.w*v1.w;
    uint4 pk;
    pk.x = f32_to_bf16_rne(v0.x) | ((unsigned)f32_to_bf16_rne(v0.y) << 16);
    pk.y = f32_to_bf16_rne(v0.z) | ((unsigned)f32_to_bf16_rne(v0.w) << 16);
    pk.z = f32_to_bf16_rne(v1.x) | ((unsigned)f32_to_bf16_rne(v1.y) << 16);
    pk.w = f32_to_bf16_rne(v1.z) | ((unsigned)f32_to_bf16_rne(v1.w) << 16);
    *(uint4*)(Xb + (size_t)row * DIM + lane * 8) = pk;
    #pragma unroll
    for (int off = 32; off; off >>= 1) s += __shfl_xor(s, off);
    if (lane == 0) sq[row] = s;
    if (blockIdx.x == 0 && threadIdx.x < 2) out[threadIdx.x] = 0.0f;
}

// One wave per triangular 64x64 Gram tile. NO LDS staging, NO barriers in the
// K-loop: fragments loaded straight from global (L1/L2-resident Xb) in the
// exact MFMA A/B register layout (lane = row m15, quad -> k-offset quad*8).
// 4-slot register ring = prefetch distance 3 k-steps.
__global__ __launch_bounds__(256, 2) void ccsa_kernel(
    const unsigned short* __restrict__ Xb, const float* __restrict__ sq,
    const int* __restrict__ ds, const int* __restrict__ y,
    const int* __restrict__ ncls, const int* __restrict__ ndom,
    float* __restrict__ out)
{
    __shared__ float red[8];

    const int wave = threadIdx.x >> 6;
    const int lane = threadIdx.x & 63;
    const int g    = blockIdx.x * 4 + wave;     // tile id, 0..NTRI-1

    // triangular decode: g -> (it <= jt) on the 64-tile grid
    int r = (int)((sqrtf(8.0f * (float)g + 1.0f) - 1.0f) * 0.5f);
    while ((r + 1) * (r + 2) / 2 <= g) ++r;
    while (r * (r + 1) / 2 > g) --r;
    const int jt   = r;
    const int it   = g - r * (r + 1) / 2;
    const bool diag = (it == jt);
    const int i0 = it * 64;
    const int j0 = jt * 64;

    const int m15  = lane & 15;
    const int quad = lane >> 4;

    // per-lane fragment base pointers: row (i0+m15), k-offset quad*8
    const unsigned short* aptr = Xb + (size_t)(i0 + m15) * DIM + quad * 8;
    const unsigned short* bptr = Xb + (size_t)(j0 + m15) * DIM + quad * 8;

    floatx4 acc[4][4];
    #pragma unroll
    for (int a = 0; a < 4; ++a)
        #pragma unroll
        for (int b = 0; b < 4; ++b)
            acc[a][b] = (floatx4){0.f, 0.f, 0.f, 0.f};

    short8 abuf[4][4], bbuf[4][4];   // 4-slot ring x 4 row-fragments

    #define LOADK(s, kt)                                                      \
        do {                                                                  \
            _Pragma("unroll")                                                 \
            for (int tt = 0; tt < 4; ++tt) {                                  \
                abuf[s][tt] = *(const short8*)(aptr + tt * 16 * DIM + (kt) * 32); \
                bbuf[s][tt] = *(const short8*)(bptr + tt * 16 * DIM + (kt) * 32); \
            }                                                                 \
        } while (0)

    LOADK(0, 0);
    LOADK(1, 1);
    LOADK(2, 2);
    #pragma unroll
    for (int kt = 0; kt < NKS; ++kt) {
        const int s = kt & 3;
        #pragma unroll
        for (int tm = 0; tm < 4; ++tm)
            #pragma unroll
            for (int tn = 0; tn < 4; ++tn)
                acc[tm][tn] = __builtin_amdgcn_mfma_f32_16x16x32_bf16(
                    abuf[s][tm], bbuf[s][tn], acc[tm][tn], 0, 0, 0);
        if (kt + 3 < NKS) LOADK((kt + 3) & 3, kt + 3);
    }
    #undef LOADK

    // Epilogue: C/D map col=lane&15, row=quad*4+reg (m89/m91 verified)
    float sqj[4]; int yj[4], dsj[4];
    #pragma unroll
    for (int tn = 0; tn < 4; ++tn) {
        const int j = j0 + tn * 16 + m15;
        sqj[tn] = sq[j]; yj[tn] = y[j]; dsj[tn] = ds[j];
    }
    float sa = 0.f, ss = 0.f;
    if (diag) {
        // both orientations inside the tile: original one-sided mask
        #pragma unroll
        for (int tm = 0; tm < 4; ++tm) {
            #pragma unroll
            for (int rr = 0; rr < 4; ++rr) {
                const int i = i0 + tm * 16 + quad * 4 + rr;
                const float sqi = sq[i];
                const int   yi  = y[i];
                const int   dsi = ds[i];
                #pragma unroll
                for (int tn = 0; tn < 4; ++tn) {
                    if (dsi < dsj[tn]) {
                        const float d2   = sqi + sqj[tn] - 2.0f * acc[tm][tn][rr];
                        const float dist = sqrtf(fmaxf(d2, 0.f));
                        if (yi == yj[tn])     sa += dist;
                        else if (yi < yj[tn]) ss += fmaxf(0.f, 1.f - dist);
                    }
                }
            }
        }
    } else {
        // off-diagonal tile: fold (i,j) and (j,i); dist is symmetric and
        // exactly one orientation has d_lt when ds_i != ds_j.
        #pragma unroll
        for (int tm = 0; tm < 4; ++tm) {
            #pragma unroll
            for (int rr = 0; rr < 4; ++rr) {
                const int i = i0 + tm * 16 + quad * 4 + rr;
                const float sqi = sq[i];
                const int   yi  = y[i];
                const int   dsi = ds[i];
                #pragma unroll
                for (int tn = 0; tn < 4; ++tn) {
                    if (dsi != dsj[tn]) {
                        const float d2   = sqi + sqj[tn] - 2.0f * acc[tm][tn][rr];
                        const float dist = sqrtf(fmaxf(d2, 0.f));
                        if (yi == yj[tn]) {
                            sa += dist;
                        } else {
                            const bool take = (dsi < dsj[tn]) ? (yi < yj[tn])
                                                              : (yj[tn] < yi);
                            if (take) ss += fmaxf(0.f, 1.f - dist);
                        }
                    }
                }
            }
        }
    }
    #pragma unroll
    for (int off = 32; off; off >>= 1) {
        sa += __shfl_xor(sa, off);
        ss += __shfl_xor(ss, off);
    }
    if (lane == 0) { red[wave] = sa; red[4 + wave] = ss; }
    __syncthreads();
    if (threadIdx.x == 0) {
        const float tsa = red[0] + red[1] + red[2] + red[3];
        const float tss = red[4] + red[5] + red[6] + red[7];
        const int nc = *ncls, nd = *ndom;
        const float n_sa = (float)(nc * (nd * (nd - 1) / 2));
        const float n_s  = (float)((nc * (nc - 1) / 2) * (nd * (nd - 1) / 2));
        atomicAdd(out + 0, tsa * 0.5f / n_sa);
        atomicAdd(out + 1, tss * 0.5f / n_s);
    }
}

extern "C" void kernel_launch(void* const* d_in, const int* in_sizes, int n_in,
                              void* d_out, int out_size, void* d_ws, size_t ws_size,
                              hipStream_t stream) {
    (void)in_sizes; (void)n_in; (void)out_size; (void)ws_size;
    const float* X  = (const float*)d_in[0];
    const int*   ds = (const int*)d_in[1];
    const int*   y  = (const int*)d_in[2];
    const int*   nc = (const int*)d_in[3];
    const int*   nd = (const int*)d_in[4];
    float* out = (float*)d_out;

    unsigned short* Xb = (unsigned short*)d_ws;                       // 4 MB bf16 X
    float* sq = (float*)((char*)d_ws + (size_t)NROW * DIM * 2);       // 16 KB norms

    prep_kernel<<<NROW / 4, 256, 0, stream>>>(X, Xb, sq, out);
    ccsa_kernel<<<NTRI / 4, 256, 0, stream>>>(Xb, sq, ds, y, nc, nd, out);
}